// Round 1
// baseline (1603.735 us; speedup 1.0000x reference)
//
#include <hip/hip_runtime.h>
#include <math.h>

typedef __attribute__((ext_vector_type(8))) short bf16x8;
typedef __attribute__((ext_vector_type(4))) float f32x4;

#define TE 64
#define LDX 392   // 384 + 8 pad (bf16 elems)
#define LDW 72    // 64 + 8
#define LDH 136   // 128 + 8

__device__ __forceinline__ short f2bf(float x) {
  union { float f; unsigned u; } c; c.f = x;
  unsigned u = c.u;
  u += 0x7fffu + ((u >> 16) & 1u);
  return (short)(u >> 16);
}
__device__ __forceinline__ float bf2f(unsigned short b) {
  union { unsigned u; float f; } c; c.u = ((unsigned)b) << 16; return c.f;
}

// ---------------- index handling ----------------
__global__ void detect_kernel(const unsigned* __restrict__ idx32, int* __restrict__ flag) {
  __shared__ int anyNZ;
  if (threadIdx.x == 0) anyNZ = 0;
  __syncthreads();
  unsigned v = idx32[threadIdx.x * 2 + 1];
  if (v != 0u) atomicOr(&anyNZ, 1);
  __syncthreads();
  if (threadIdx.x == 0) *flag = (anyNZ == 0) ? 1 : 0;  // 1 => int64 input
}

__global__ void convert_idx_kernel(const void* __restrict__ in, int* __restrict__ s32,
                                   const int* __restrict__ flag, int twoE) {
  int i = blockIdx.x * 256 + threadIdx.x;
  if (i >= twoE) return;
  int f = *flag;
  int v = f ? (int)((const long long*)in)[i] : ((const int*)in)[i];
  s32[i] = v;
}

__global__ void count_kernel(const int* __restrict__ src, int* __restrict__ cnt, int E) {
  int i = blockIdx.x * 256 + threadIdx.x;
  if (i < E) atomicAdd(&cnt[src[i]], 1);
}

__global__ void __launch_bounds__(1024)
scan_kernel(const int* __restrict__ cnt, int* __restrict__ offs, int n) {
  __shared__ int sp[1024];
  int t = threadIdx.x;
  int chunk = (n + 1023) / 1024;
  int begin = t * chunk;
  int end = begin + chunk; if (end > n) end = n; if (begin > n) begin = n;
  int s = 0;
  for (int i = begin; i < end; ++i) s += cnt[i];
  sp[t] = s;
  __syncthreads();
  for (int o = 1; o < 1024; o <<= 1) {
    int v = (t >= o) ? sp[t - o] : 0;
    __syncthreads();
    sp[t] += v;
    __syncthreads();
  }
  int run = (t == 0) ? 0 : sp[t - 1];
  for (int i = begin; i < end; ++i) { offs[i] = run; run += cnt[i]; }
  if (t == 0) offs[n] = sp[1023];
}

__global__ void scatter_kernel(const int* __restrict__ src, const int* __restrict__ offs,
                               int* __restrict__ cur, int* __restrict__ order, int E) {
  int i = blockIdx.x * 256 + threadIdx.x;
  if (i >= E) return;
  int s = src[i];
  int p = offs[s] + atomicAdd(&cur[s], 1);
  order[p] = i;
}

// ---------------- weight fp32 -> bf16 ----------------
// layout in out: W1[128*384] | W2[128*128] | W3[4*128] | Wv[128*128] | Wo[128*128] | Wg[128*128]
__global__ void wcvt_kernel(const float* __restrict__ B1, const float* __restrict__ B2,
                            const float* __restrict__ B3, const float* __restrict__ Wv,
                            const float* __restrict__ Wo, const float* __restrict__ Wg,
                            short* __restrict__ o) {
  int i = blockIdx.x * 256 + threadIdx.x;
  const float* s; int base;
  if (i < 49152)       { s = B1; base = 0; }
  else if (i < 65536)  { s = B2; base = 49152; }
  else if (i < 66048)  { s = B3; base = 65536; }
  else if (i < 82432)  { s = Wv; base = 66048; }
  else if (i < 98816)  { s = Wo; base = 82432; }
  else if (i < 115200) { s = Wg; base = 98816; }
  else return;
  o[i] = f2bf(s[i - base]);
}

// ---------------- edge kernel ----------------
template<int KT, int LDA>
__device__ __forceinline__ void mm_tile(const short (*A)[LDA], int aOff,
                                        const short* __restrict__ Wg,
                                        short (*sW)[LDW], f32x4 acc[2][4], int t) {
  const int lane = t & 63;
  const int wid = t >> 6;
  const int mBase = (wid >> 1) * 32;
  const int nBase = (wid & 1) * 64;
  const int lrow = lane & 15;
  const int kgrp = lane >> 4;
  for (int kc = 0; kc < KT; kc += 64) {
    __syncthreads();
#pragma unroll
    for (int i = 0; i < 4; ++i) {
      int r = (t >> 3) + i * 32;
      int c = (t & 7) * 8;
      *(uint4*)&sW[r][c] = *(const uint4*)(Wg + (size_t)r * KT + kc + c);
    }
    __syncthreads();
#pragma unroll
    for (int ks = 0; ks < 64; ks += 32) {
      bf16x8 a0 = *(const bf16x8*)&A[mBase + lrow][aOff + kc + ks + kgrp * 8];
      bf16x8 a1 = *(const bf16x8*)&A[mBase + 16 + lrow][aOff + kc + ks + kgrp * 8];
#pragma unroll
      for (int nf = 0; nf < 4; ++nf) {
        bf16x8 b = *(const bf16x8*)&sW[nBase + nf * 16 + lrow][ks + kgrp * 8];
        acc[0][nf] = __builtin_amdgcn_mfma_f32_16x16x32_bf16(a0, b, acc[0][nf], 0, 0, 0);
        acc[1][nf] = __builtin_amdgcn_mfma_f32_16x16x32_bf16(a1, b, acc[1][nf], 0, 0, 0);
      }
    }
  }
}

__global__ void __launch_bounds__(256, 1)
edge_kernel(const float* __restrict__ hV, const float* __restrict__ hE,
            const int* __restrict__ src, const int* __restrict__ dst,
            const short* __restrict__ W1, const float* __restrict__ b1,
            const short* __restrict__ W2, const float* __restrict__ b2,
            const short* __restrict__ W3, const float* __restrict__ b3,
            const short* __restrict__ Wv, const float* __restrict__ bv,
            float* __restrict__ logits, short* __restrict__ Vout, int E) {
  __shared__ short sX[TE][LDX];
  __shared__ short sW[128][LDW];
  __shared__ short sX2[TE][LDH];
  __shared__ short sOut[TE][LDH];
  __shared__ short sW3[4][128];

  const int t = threadIdx.x;
  const int eBase = blockIdx.x * TE;
  const int lane = t & 63;
  const int wid = t >> 6;
  const int mBase = (wid >> 1) * 32;
  const int nBase = (wid & 1) * 64;
  const int lrow = lane & 15;
  const int kgrp = lane >> 4;

  // stage X = [hV[src] | hE | hV[dst]] (bf16)
#pragma unroll
  for (int i = 0; i < 24; ++i) {
    int flat = t + i * 256;         // 0..6143
    int row = flat / 96;
    int c4 = (flat % 96) * 4;       // float col
    int e = eBase + row;
    float4 v = make_float4(0.f, 0.f, 0.f, 0.f);
    if (e < E) {
      const float* p;
      if (c4 < 128)       p = hV + (size_t)src[e] * 128 + c4;
      else if (c4 < 256)  p = hE + (size_t)e * 128 + (c4 - 128);
      else                p = hV + (size_t)dst[e] * 128 + (c4 - 256);
      v = *(const float4*)p;
    }
    sX[row][c4]     = f2bf(v.x);
    sX[row][c4 + 1] = f2bf(v.y);
    sX[row][c4 + 2] = f2bf(v.z);
    sX[row][c4 + 3] = f2bf(v.w);
  }
  for (int i = t; i < 512; i += 256) ((short*)sW3)[i] = W3[i];

  f32x4 acc[2][4];

  // ---- layer 1: X[64,384] @ W1.T -> relu -> sX2
#pragma unroll
  for (int mi = 0; mi < 2; ++mi)
#pragma unroll
    for (int nf = 0; nf < 4; ++nf)
#pragma unroll
      for (int q = 0; q < 4; ++q) acc[mi][nf][q] = 0.f;
  mm_tile<384, LDX>(sX, 0, W1, sW, acc, t);
#pragma unroll
  for (int mi = 0; mi < 2; ++mi)
#pragma unroll
    for (int nf = 0; nf < 4; ++nf)
#pragma unroll
      for (int q = 0; q < 4; ++q) {
        int row = mBase + mi * 16 + kgrp * 4 + q;
        int col = nBase + nf * 16 + lrow;
        float x = acc[mi][nf][q] + b1[col];
        sX2[row][col] = f2bf(fmaxf(x, 0.f));
      }

  // ---- V = gelu(hE @ Wv.T + bv) -> global bf16
#pragma unroll
  for (int mi = 0; mi < 2; ++mi)
#pragma unroll
    for (int nf = 0; nf < 4; ++nf)
#pragma unroll
      for (int q = 0; q < 4; ++q) acc[mi][nf][q] = 0.f;
  mm_tile<128, LDX>(sX, 128, Wv, sW, acc, t);
#pragma unroll
  for (int mi = 0; mi < 2; ++mi)
#pragma unroll
    for (int nf = 0; nf < 4; ++nf)
#pragma unroll
      for (int q = 0; q < 4; ++q) {
        int row = mBase + mi * 16 + kgrp * 4 + q;
        int col = nBase + nf * 16 + lrow;
        float x = acc[mi][nf][q] + bv[col];
        float g = 0.5f * x * (1.0f + erff(x * 0.70710678118654752f));
        sOut[row][col] = f2bf(g);
      }
  __syncthreads();
#pragma unroll
  for (int i = 0; i < 4; ++i) {
    int flat = t + i * 256;        // 0..1023 uint4s
    int row = flat >> 4;
    int c8 = (flat & 15) * 8;
    int e = eBase + row;
    if (e < E) *(uint4*)(Vout + (size_t)e * 128 + c8) = *(const uint4*)&sOut[row][c8];
  }

  // ---- layer 2: sX2 @ W2.T -> relu -> sOut
#pragma unroll
  for (int mi = 0; mi < 2; ++mi)
#pragma unroll
    for (int nf = 0; nf < 4; ++nf)
#pragma unroll
      for (int q = 0; q < 4; ++q) acc[mi][nf][q] = 0.f;
  mm_tile<128, LDH>(sX2, 0, W2, sW, acc, t);
#pragma unroll
  for (int mi = 0; mi < 2; ++mi)
#pragma unroll
    for (int nf = 0; nf < 4; ++nf)
#pragma unroll
      for (int q = 0; q < 4; ++q) {
        int row = mBase + mi * 16 + kgrp * 4 + q;
        int col = nBase + nf * 16 + lrow;
        float x = acc[mi][nf][q] + b2[col];
        sOut[row][col] = f2bf(fmaxf(x, 0.f));
      }
  __syncthreads();

  // ---- layer 3: logits[e][h] = (x2 . W3[h] + b3[h]) / sqrt(32)
  {
    int r = t >> 2, h = t & 3;
    float s = 0.f;
    for (int d = 0; d < 128; ++d)
      s += bf2f((unsigned short)sOut[r][d]) * bf2f((unsigned short)sW3[h][d]);
    s = (s + b3[h]) * 0.17677669529663687f;
    int e = eBase + r;
    if (e < E) logits[(size_t)e * 4 + h] = s;
  }
}

// ---------------- node kernel ----------------
__device__ __forceinline__ float dot8(const float* ag, uint4 w) {
  unsigned wr[4] = {w.x, w.y, w.z, w.w};
  float s = 0.f;
#pragma unroll
  for (int q = 0; q < 4; ++q) {
    s += ag[2 * q]     * bf2f((unsigned short)(wr[q] & 0xffffu));
    s += ag[2 * q + 1] * bf2f((unsigned short)(wr[q] >> 16));
  }
  return s;
}

__global__ void __launch_bounds__(256)
node_kernel(const float* __restrict__ hV, const float* __restrict__ logits,
            const unsigned short* __restrict__ Vb,
            const int* __restrict__ offs, const int* __restrict__ order,
            const short* __restrict__ Wo, const short* __restrict__ Wg,
            const float* __restrict__ gb, float* __restrict__ out, int nN) {
  __shared__ float sAgg[4][132];
  const int wid = threadIdx.x >> 6;
  const int lane = threadIdx.x & 63;
  const int head = lane >> 4;
  const int nW = gridDim.x * 4;
  for (int v = blockIdx.x * 4 + wid; v < nN; v += nW) {
    const int base = offs[v];
    const int deg = offs[v + 1] - base;
    float m0 = -1e30f, m1 = -1e30f, m2 = -1e30f, m3 = -1e30f;
    for (int i = lane; i < deg; i += 64) {
      int e = order[base + i];
      float4 lg = *(const float4*)(logits + (size_t)e * 4);
      m0 = fmaxf(m0, lg.x); m1 = fmaxf(m1, lg.y);
      m2 = fmaxf(m2, lg.z); m3 = fmaxf(m3, lg.w);
    }
#pragma unroll
    for (int o = 32; o > 0; o >>= 1) {
      m0 = fmaxf(m0, __shfl_xor(m0, o));
      m1 = fmaxf(m1, __shfl_xor(m1, o));
      m2 = fmaxf(m2, __shfl_xor(m2, o));
      m3 = fmaxf(m3, __shfl_xor(m3, o));
    }
    const float mhead = (head == 0) ? m0 : (head == 1) ? m1 : (head == 2) ? m2 : m3;
    float dsum = 0.f, a0 = 0.f, a1 = 0.f;
    for (int i0 = 0; i0 < deg; i0 += 64) {
      int cnt = deg - i0; if (cnt > 64) cnt = 64;
      int ordv = (i0 + lane < deg) ? order[base + i0 + lane] : 0;
      for (int i = 0; i < cnt; ++i) {
        int e = __shfl(ordv, i);
        float lg = logits[(size_t)e * 4 + head];
        unsigned pv = *(const unsigned*)(Vb + (size_t)e * 128 + 2 * lane);
        float ex = __expf(lg - mhead);
        dsum += ex;
        a0 += ex * bf2f((unsigned short)(pv & 0xffffu));
        a1 += ex * bf2f((unsigned short)(pv >> 16));
      }
    }
    float inv = (dsum > 0.f) ? 1.f / dsum : 0.f;
    sAgg[wid][2 * lane]     = a0 * inv;
    sAgg[wid][2 * lane + 1] = a1 * inv;
    asm volatile("s_waitcnt lgkmcnt(0)" ::: "memory");
    __builtin_amdgcn_wave_barrier();
    const int j0 = lane, j1 = lane + 64;
    float d0 = 0.f, d1 = 0.f, g0 = 0.f, g1 = 0.f;
#pragma unroll 4
    for (int d = 0; d < 128; d += 8) {
      float ag[8];
#pragma unroll
      for (int q = 0; q < 8; ++q) ag[q] = sAgg[wid][d + q];
      uint4 wo0 = *(const uint4*)(Wo + (size_t)j0 * 128 + d);
      uint4 wo1 = *(const uint4*)(Wo + (size_t)j1 * 128 + d);
      uint4 wg0 = *(const uint4*)(Wg + (size_t)j0 * 128 + d);
      uint4 wg1 = *(const uint4*)(Wg + (size_t)j1 * 128 + d);
      d0 += dot8(ag, wo0); d1 += dot8(ag, wo1);
      g0 += dot8(ag, wg0); g1 += dot8(ag, wg1);
    }
    float gg0 = 1.f / (1.f + __expf(-(g0 + gb[j0])));
    float gg1 = 1.f / (1.f + __expf(-(g1 + gb[j1])));
    out[(size_t)v * 128 + j0] = hV[(size_t)v * 128 + j0] + d0 * gg0;
    out[(size_t)v * 128 + j1] = hV[(size_t)v * 128 + j1] + d1 * gg1;
    __builtin_amdgcn_wave_barrier();
  }
}

// ---------------- fallback (ws too small marker) ----------------
__global__ void fb_kernel(const float* __restrict__ hV, float* __restrict__ out, int n) {
  int i = blockIdx.x * 256 + threadIdx.x;
  if (i < n) out[i] = hV[i] + 0.5f;
}

extern "C" void kernel_launch(void* const* d_in, const int* in_sizes, int n_in,
                              void* d_out, int out_size, void* d_ws, size_t ws_size,
                              hipStream_t stream) {
  const float* hV   = (const float*)d_in[0];
  const float* hE   = (const float*)d_in[1];
  const void*  eidx = d_in[2];
  const float* WvW  = (const float*)d_in[3];
  const float* WvB  = (const float*)d_in[4];
  const float* B1w  = (const float*)d_in[5];
  const float* B1b  = (const float*)d_in[6];
  const float* B2w  = (const float*)d_in[7];
  const float* B2b  = (const float*)d_in[8];
  const float* B3w  = (const float*)d_in[9];
  const float* B3b  = (const float*)d_in[10];
  const float* WoW  = (const float*)d_in[11];
  const float* GW   = (const float*)d_in[12];
  const float* GB   = (const float*)d_in[13];

  const int Nn = in_sizes[0] / 128;
  const int E  = in_sizes[1] / 128;
  if (Nn <= 0 || E <= 0) return;

  char* ws = (char*)d_ws;
  size_t off = 0;
  auto alloc = [&](size_t b) { size_t o = off; off += (b + 255) & ~(size_t)255; return o; };
  const size_t o_idx   = alloc((size_t)2 * E * 4);
  const size_t o_cnt   = alloc((size_t)(Nn + 1) * 4);
  const size_t o_offs  = alloc((size_t)(Nn + 1) * 4);
  const size_t o_cur   = alloc((size_t)Nn * 4);
  const size_t o_order = alloc((size_t)E * 4);
  const size_t o_flag  = alloc(256);
  const size_t o_log   = alloc((size_t)E * 16);
  const size_t o_V     = alloc((size_t)E * 256);
  const size_t o_wbf   = alloc((size_t)115200 * 2);

  if (off > ws_size) {
    fb_kernel<<<(out_size + 255) / 256, 256, 0, stream>>>(hV, (float*)d_out, out_size);
    return;
  }

  int*   idx32  = (int*)(ws + o_idx);
  int*   cnt    = (int*)(ws + o_cnt);
  int*   offsP  = (int*)(ws + o_offs);
  int*   cur    = (int*)(ws + o_cur);
  int*   order  = (int*)(ws + o_order);
  int*   flag   = (int*)(ws + o_flag);
  float* logits = (float*)(ws + o_log);
  short* Vb     = (short*)(ws + o_V);
  short* wbf    = (short*)(ws + o_wbf);

  short* W1b = wbf;
  short* W2b = wbf + 49152;
  short* W3b = wbf + 65536;
  short* Wvb = wbf + 66048;
  short* Wob = wbf + 82432;
  short* Wgb = wbf + 98816;

  const int* src = idx32;
  const int* dst = idx32 + E;

  detect_kernel<<<1, 256, 0, stream>>>((const unsigned*)eidx, flag);
  convert_idx_kernel<<<(2 * E + 255) / 256, 256, 0, stream>>>(eidx, idx32, flag, 2 * E);
  hipMemsetAsync(cnt, 0, (size_t)(Nn + 1) * 4, stream);
  hipMemsetAsync(cur, 0, (size_t)Nn * 4, stream);
  count_kernel<<<(E + 255) / 256, 256, 0, stream>>>(src, cnt, E);
  scan_kernel<<<1, 1024, 0, stream>>>(cnt, offsP, Nn);
  scatter_kernel<<<(E + 255) / 256, 256, 0, stream>>>(src, offsP, cur, order, E);
  wcvt_kernel<<<(115200 + 255) / 256, 256, 0, stream>>>(B1w, B2w, B3w, WvW, WoW, GW, wbf);

  edge_kernel<<<(E + TE - 1) / TE, 256, 0, stream>>>(
      hV, hE, src, dst, W1b, B1b, W2b, B2b, W3b, B3b, Wvb, WvB, logits, Vb, E);

  node_kernel<<<1024, 256, 0, stream>>>(
      hV, logits, (const unsigned short*)Vb, offsP, order, Wob, Wgb, GB,
      (float*)d_out, Nn);
}

// Round 2
// 1114.196 us; speedup vs baseline: 1.4394x; 1.4394x over previous
//
#include <hip/hip_runtime.h>
#include <math.h>

typedef __attribute__((ext_vector_type(8))) short bf16x8;
typedef __attribute__((ext_vector_type(4))) float f32x4;

#define TE2 128
#define LDA 72    // 64 + 8 pad (bf16), row stride 144B = 9 x 16B (odd) -> conflict-free b128
#define LDH 136   // 128 + 8 pad, stride 272B = 17 x 16B (odd)

__device__ __forceinline__ short f2bf(float x) {
  union { float f; unsigned u; } c; c.f = x;
  unsigned u = c.u;
  u += 0x7fffu + ((u >> 16) & 1u);
  return (short)(u >> 16);
}
__device__ __forceinline__ float bf2f(unsigned short b) {
  union { unsigned u; float f; } c; c.u = ((unsigned)b) << 16; return c.f;
}
__device__ __forceinline__ unsigned pack2(float a, float b) {
  return ((unsigned)(unsigned short)f2bf(a)) | (((unsigned)(unsigned short)f2bf(b)) << 16);
}

// ---------------- index handling ----------------
__global__ void detect_kernel(const unsigned* __restrict__ idx32, int* __restrict__ flag) {
  __shared__ int anyNZ;
  if (threadIdx.x == 0) anyNZ = 0;
  __syncthreads();
  unsigned v = idx32[threadIdx.x * 2 + 1];
  if (v != 0u) atomicOr(&anyNZ, 1);
  __syncthreads();
  if (threadIdx.x == 0) *flag = (anyNZ == 0) ? 1 : 0;  // 1 => int64 input
}

__global__ void convert_idx_kernel(const void* __restrict__ in, int* __restrict__ s32,
                                   const int* __restrict__ flag, int twoE) {
  int i = blockIdx.x * 256 + threadIdx.x;
  if (i >= twoE) return;
  int f = *flag;
  int v = f ? (int)((const long long*)in)[i] : ((const int*)in)[i];
  s32[i] = v;
}

__global__ void count_kernel(const int* __restrict__ src, int* __restrict__ cnt, int E) {
  int i = blockIdx.x * 256 + threadIdx.x;
  if (i < E) atomicAdd(&cnt[src[i]], 1);
}

__global__ void __launch_bounds__(1024)
scan_kernel(const int* __restrict__ cnt, int* __restrict__ offs, int n) {
  __shared__ int sp[1024];
  int t = threadIdx.x;
  int chunk = (n + 1023) / 1024;
  int begin = t * chunk;
  int end = begin + chunk; if (end > n) end = n; if (begin > n) begin = n;
  int s = 0;
  for (int i = begin; i < end; ++i) s += cnt[i];
  sp[t] = s;
  __syncthreads();
  for (int o = 1; o < 1024; o <<= 1) {
    int v = (t >= o) ? sp[t - o] : 0;
    __syncthreads();
    sp[t] += v;
    __syncthreads();
  }
  int run = (t == 0) ? 0 : sp[t - 1];
  for (int i = begin; i < end; ++i) { offs[i] = run; run += cnt[i]; }
  if (t == 0) offs[n] = sp[1023];
}

__global__ void scatter_kernel(const int* __restrict__ src, const int* __restrict__ offs,
                               int* __restrict__ cur, int* __restrict__ order, int E) {
  int i = blockIdx.x * 256 + threadIdx.x;
  if (i >= E) return;
  int s = src[i];
  int p = offs[s] + atomicAdd(&cur[s], 1);
  order[p] = i;
}

// ---------------- weight fp32 -> bf16 ----------------
// layout: W1[128*384] | W2[128*128] | W3[4*128] | Wv[128*128] | Wo[128*128] | Wg[128*128]
__global__ void wcvt_kernel(const float* __restrict__ B1, const float* __restrict__ B2,
                            const float* __restrict__ B3, const float* __restrict__ Wv,
                            const float* __restrict__ Wo, const float* __restrict__ Wg,
                            short* __restrict__ o) {
  int i = blockIdx.x * 256 + threadIdx.x;
  const float* s; int base;
  if (i < 49152)       { s = B1; base = 0; }
  else if (i < 65536)  { s = B2; base = 49152; }
  else if (i < 66048)  { s = B3; base = 65536; }
  else if (i < 82432)  { s = Wv; base = 66048; }
  else if (i < 98816)  { s = Wo; base = 82432; }
  else if (i < 115200) { s = Wg; base = 98816; }
  else return;
  o[i] = f2bf(s[i - base]);
}

// ---------------- edge kernel (128 edges/block, 4 waves, 64x64 wave tiles) -----------
template<int LD>
__device__ __forceinline__ void mm_chunk(const short (*A)[LD], int aRow, int aCol,
                                         const short (*B)[LDA], int bRow,
                                         f32x4 acc[4][4], int lrow, int kgrp) {
#pragma unroll
  for (int ks = 0; ks < 64; ks += 32) {
    bf16x8 a[4];
#pragma unroll
    for (int mi = 0; mi < 4; ++mi)
      a[mi] = *(const bf16x8*)&A[aRow + mi * 16 + lrow][aCol + ks + kgrp * 8];
#pragma unroll
    for (int nf = 0; nf < 4; ++nf) {
      bf16x8 b = *(const bf16x8*)&B[bRow + nf * 16 + lrow][ks + kgrp * 8];
#pragma unroll
      for (int mi = 0; mi < 4; ++mi)
        acc[mi][nf] = __builtin_amdgcn_mfma_f32_16x16x32_bf16(a[mi], b, acc[mi][nf], 0, 0, 0);
    }
  }
}

__global__ void __launch_bounds__(256, 2)
edge_kernel(const float* __restrict__ hV, const float* __restrict__ hE,
            const int* __restrict__ src, const int* __restrict__ dst,
            const short* __restrict__ W1, const float* __restrict__ b1,
            const short* __restrict__ W2, const float* __restrict__ b2,
            const short* __restrict__ W3, const float* __restrict__ b3,
            const short* __restrict__ Wv, const float* __restrict__ bv,
            float* __restrict__ logits, short* __restrict__ Vout, int E) {
  __shared__ int sSrc[TE2];
  __shared__ int sDst[TE2];
  __shared__ short sA[TE2][LDA];
  __shared__ short sB[128][LDA];
  __shared__ short sH[TE2][LDH];
  __shared__ float sPart[TE2][4][2];

  const int t = threadIdx.x;
  const int eBase = blockIdx.x * TE2;
  const int lane = t & 63;
  const int wid = t >> 6;
  const int wrow = (wid >> 1) * 64;
  const int wcol = (wid & 1) * 64;
  const int lrow = lane & 15;
  const int kgrp = lane >> 4;

  if (t < 128) { int e = eBase + t; sSrc[t] = (e < E) ? src[e] : 0; }
  else         { int e = eBase + (t - 128); sDst[t - 128] = (e < E) ? dst[e] : 0; }

  // stage 64 fp32 cols of X (gathered) into sA as bf16. k0 in {0,64,128,192,256,320}
  auto stageA = [&](int k0) {
    const int cls = k0 >> 7;       // 0: hV[src], 1: hE, 2: hV[dst]
    const int cbase = k0 & 127;
#pragma unroll
    for (int i = 0; i < 4; ++i) {
      int flat = t + i * 256;
      int row = flat >> 3;
      int seg = (flat & 7) * 8;    // float col within chunk
      int e = eBase + row;
      const float* p;
      if (cls == 0)      p = hV + (size_t)sSrc[row] * 128 + cbase + seg;
      else if (cls == 1) p = hE + (size_t)e * 128 + cbase + seg;
      else               p = hV + (size_t)sDst[row] * 128 + cbase + seg;
      float4 v0 = make_float4(0.f, 0.f, 0.f, 0.f), v1 = v0;
      if (e < E) { v0 = *(const float4*)p; v1 = *(const float4*)(p + 4); }
      uint4 u;
      u.x = pack2(v0.x, v0.y); u.y = pack2(v0.z, v0.w);
      u.z = pack2(v1.x, v1.y); u.w = pack2(v1.z, v1.w);
      *(uint4*)&sA[row][seg] = u;
    }
  };

  auto stageB = [&](const short* __restrict__ W, int ldw, int k0) {
#pragma unroll
    for (int i = 0; i < 4; ++i) {
      int flat = t + i * 256;
      int row = flat >> 3;
      int seg = (flat & 7) * 8;
      *(uint4*)&sB[row][seg] = *(const uint4*)(W + (size_t)row * ldw + k0 + seg);
    }
  };

  f32x4 acc[4][4];
  auto zacc = [&]() {
#pragma unroll
    for (int mi = 0; mi < 4; ++mi)
#pragma unroll
      for (int nf = 0; nf < 4; ++nf)
#pragma unroll
        for (int q = 0; q < 4; ++q) acc[mi][nf][q] = 0.f;
  };

  // ---------------- layer 1: relu(X[128,384] @ W1.T + b1) -> sH ----------------
  zacc();
#pragma unroll 1
  for (int c = 0; c < 6; ++c) {
    int k0 = c * 64;
    __syncthreads();
    stageA(k0);
    stageB(W1, 384, k0);
    __syncthreads();
    mm_chunk<LDA>(sA, wrow, 0, sB, wcol, acc, lrow, kgrp);
  }
  {
    float b1c[4];
#pragma unroll
    for (int nf = 0; nf < 4; ++nf) b1c[nf] = b1[wcol + nf * 16 + lrow];
#pragma unroll
    for (int mi = 0; mi < 4; ++mi)
#pragma unroll
      for (int nf = 0; nf < 4; ++nf)
#pragma unroll
        for (int q = 0; q < 4; ++q) {
          int row = wrow + mi * 16 + kgrp * 4 + q;
          int col = wcol + nf * 16 + lrow;
          sH[row][col] = f2bf(fmaxf(acc[mi][nf][q] + b1c[nf], 0.f));
        }
  }

  // ---------------- layer 2: relu(sH @ W2.T + b2), fold layer 3 into epilogue -------
  zacc();
#pragma unroll 1
  for (int c = 0; c < 2; ++c) {
    int k0 = c * 64;
    __syncthreads();
    stageB(W2, 128, k0);
    __syncthreads();
    mm_chunk<LDH>(sH, wrow, k0, sB, wcol, acc, lrow, kgrp);
  }
  {
    float b2c[4], w3v[4][4];
#pragma unroll
    for (int nf = 0; nf < 4; ++nf) {
      int col = wcol + nf * 16 + lrow;
      b2c[nf] = b2[col];
#pragma unroll
      for (int h = 0; h < 4; ++h) w3v[h][nf] = bf2f((unsigned short)W3[h * 128 + col]);
    }
#pragma unroll
    for (int mi = 0; mi < 4; ++mi)
#pragma unroll
      for (int q = 0; q < 4; ++q) {
        float p0 = 0.f, p1 = 0.f, p2 = 0.f, p3 = 0.f;
#pragma unroll
        for (int nf = 0; nf < 4; ++nf) {
          float x = fmaxf(acc[mi][nf][q] + b2c[nf], 0.f);
          p0 += x * w3v[0][nf]; p1 += x * w3v[1][nf];
          p2 += x * w3v[2][nf]; p3 += x * w3v[3][nf];
        }
#pragma unroll
        for (int o = 1; o < 16; o <<= 1) {
          p0 += __shfl_xor(p0, o); p1 += __shfl_xor(p1, o);
          p2 += __shfl_xor(p2, o); p3 += __shfl_xor(p3, o);
        }
        if (lrow < 4) {
          float pw = (lrow == 0) ? p0 : (lrow == 1) ? p1 : (lrow == 2) ? p2 : p3;
          sPart[wrow + mi * 16 + kgrp * 4 + q][lrow][wid & 1] = pw;
        }
      }
  }
  __syncthreads();
#pragma unroll
  for (int it = 0; it < 2; ++it) {
    int item = t * 2 + it;
    int r = item >> 2, h = item & 3;
    float lg = (sPart[r][h][0] + sPart[r][h][1] + b3[h]) * 0.17677669529663687f;
    int e = eBase + r;
    if (e < E) logits[(size_t)e * 4 + h] = lg;
  }

  // ---------------- V = gelu(hE @ Wv.T + bv) -> global bf16 ----------------
  zacc();
#pragma unroll 1
  for (int c = 0; c < 2; ++c) {
    int k0 = c * 64;
    __syncthreads();
    stageA(128 + k0);
    stageB(Wv, 128, k0);
    __syncthreads();
    mm_chunk<LDA>(sA, wrow, 0, sB, wcol, acc, lrow, kgrp);
  }
  {
    float bvc[4];
#pragma unroll
    for (int nf = 0; nf < 4; ++nf) bvc[nf] = bv[wcol + nf * 16 + lrow];
    __syncthreads();   // sH no longer read; safe to overwrite
#pragma unroll
    for (int mi = 0; mi < 4; ++mi)
#pragma unroll
      for (int nf = 0; nf < 4; ++nf)
#pragma unroll
        for (int q = 0; q < 4; ++q) {
          int row = wrow + mi * 16 + kgrp * 4 + q;
          int col = wcol + nf * 16 + lrow;
          float x = acc[mi][nf][q] + bvc[nf];
          float g = 0.5f * x * (1.0f + erff(x * 0.70710678118654752f));
          sH[row][col] = f2bf(g);
        }
  }
  __syncthreads();
#pragma unroll
  for (int i = 0; i < 4; ++i) {
    int flat = t + i * 256;
    int row = flat >> 3;
    int c8 = (flat & 7) * 8;
    int e = eBase + row;
    if (e < E) *(uint4*)(Vout + (size_t)e * 128 + c8) = *(const uint4*)&sH[row][c8];
  }
}

// ---------------- node kernels ----------------
// Phase 1: per-node max + exp + denom; stores unnormalized exp weights and 1/denom.
__global__ void __launch_bounds__(256)
nm_kernel(const float* __restrict__ logits, const int* __restrict__ offs,
          const int* __restrict__ order, float* __restrict__ attw,
          float* __restrict__ inv, int nN) {
  const int wid = threadIdx.x >> 6, lane = threadIdx.x & 63;
  const int nW = gridDim.x * 4;
  for (int v = blockIdx.x * 4 + wid; v < nN; v += nW) {
    const int base = offs[v];
    const int deg = offs[v + 1] - base;
    float m0 = -3e38f, m1 = -3e38f, m2 = -3e38f, m3 = -3e38f;
    for (int i = lane; i < deg; i += 64) {
      int e = order[base + i];
      float4 l = *(const float4*)(logits + (size_t)e * 4);
      m0 = fmaxf(m0, l.x); m1 = fmaxf(m1, l.y);
      m2 = fmaxf(m2, l.z); m3 = fmaxf(m3, l.w);
    }
#pragma unroll
    for (int o = 32; o > 0; o >>= 1) {
      m0 = fmaxf(m0, __shfl_xor(m0, o)); m1 = fmaxf(m1, __shfl_xor(m1, o));
      m2 = fmaxf(m2, __shfl_xor(m2, o)); m3 = fmaxf(m3, __shfl_xor(m3, o));
    }
    float d0 = 0.f, d1 = 0.f, d2 = 0.f, d3 = 0.f;
    for (int i = lane; i < deg; i += 64) {
      int e = order[base + i];
      float4 l = *(const float4*)(logits + (size_t)e * 4);
      float4 ex;
      ex.x = __expf(l.x - m0); ex.y = __expf(l.y - m1);
      ex.z = __expf(l.z - m2); ex.w = __expf(l.w - m3);
      *(float4*)(attw + (size_t)e * 4) = ex;
      d0 += ex.x; d1 += ex.y; d2 += ex.z; d3 += ex.w;
    }
#pragma unroll
    for (int o = 32; o > 0; o >>= 1) {
      d0 += __shfl_xor(d0, o); d1 += __shfl_xor(d1, o);
      d2 += __shfl_xor(d2, o); d3 += __shfl_xor(d3, o);
    }
    if (lane < 4) {
      float dv = (lane == 0) ? d0 : (lane == 1) ? d1 : (lane == 2) ? d2 : d3;
      inv[(size_t)v * 4 + lane] = (dv > 0.f) ? 1.f / dv : 0.f;
    }
  }
}

__device__ __forceinline__ float dot8(const float* ag, uint4 w) {
  unsigned wr[4] = {w.x, w.y, w.z, w.w};
  float s = 0.f;
#pragma unroll
  for (int q = 0; q < 4; ++q) {
    s += ag[2 * q]     * bf2f((unsigned short)(wr[q] & 0xffffu));
    s += ag[2 * q + 1] * bf2f((unsigned short)(wr[q] >> 16));
  }
  return s;
}

// Phase 2: dim-parallel aggregation (coalesced V rows) + fused output GEMV. 4 nodes/block.
__global__ void __launch_bounds__(512)
agg_kernel(const float* __restrict__ hV, const float* __restrict__ attw,
           const float* __restrict__ inv, const unsigned short* __restrict__ V,
           const int* __restrict__ offs, const int* __restrict__ order,
           const short* __restrict__ Wo, const short* __restrict__ Wg,
           const float* __restrict__ gb, float* __restrict__ out, int nN) {
  __shared__ float sAgg[4][132];
  const int vl = threadIdx.x >> 7;
  const int d = threadIdx.x & 127;
  const int h = d >> 5;
  const int v = blockIdx.x * 4 + vl;
  if (v < nN) {
    const int base = offs[v];
    const int deg = offs[v + 1] - base;
    float s = 0.f;
    for (int i = 0; i < deg; ++i) {
      int e = order[base + i];
      s += attw[(size_t)e * 4 + h] * bf2f(V[(size_t)e * 128 + d]);
    }
    sAgg[vl][d] = s * inv[(size_t)v * 4 + h];
  }
  __syncthreads();
  if (v < nN) {
    float o = 0.f, g = 0.f;
#pragma unroll 4
    for (int k = 0; k < 128; k += 8) {
      float a8[8];
#pragma unroll
      for (int q = 0; q < 8; ++q) a8[q] = sAgg[vl][k + q];
      uint4 wo = *(const uint4*)(Wo + (size_t)d * 128 + k);
      uint4 wg = *(const uint4*)(Wg + (size_t)d * 128 + k);
      o += dot8(a8, wo);
      g += dot8(a8, wg);
    }
    float gate = 1.f / (1.f + __expf(-(g + gb[d])));
    out[(size_t)v * 128 + d] = hV[(size_t)v * 128 + d] + o * gate;
  }
}

// ---------------- fallback (ws too small marker) ----------------
__global__ void fb_kernel(const float* __restrict__ hV, float* __restrict__ out, int n) {
  int i = blockIdx.x * 256 + threadIdx.x;
  if (i < n) out[i] = hV[i] + 0.5f;
}

extern "C" void kernel_launch(void* const* d_in, const int* in_sizes, int n_in,
                              void* d_out, int out_size, void* d_ws, size_t ws_size,
                              hipStream_t stream) {
  const float* hV   = (const float*)d_in[0];
  const float* hE   = (const float*)d_in[1];
  const void*  eidx = d_in[2];
  const float* WvW  = (const float*)d_in[3];
  const float* WvB  = (const float*)d_in[4];
  const float* B1w  = (const float*)d_in[5];
  const float* B1b  = (const float*)d_in[6];
  const float* B2w  = (const float*)d_in[7];
  const float* B2b  = (const float*)d_in[8];
  const float* B3w  = (const float*)d_in[9];
  const float* B3b  = (const float*)d_in[10];
  const float* WoW  = (const float*)d_in[11];
  const float* GW   = (const float*)d_in[12];
  const float* GB   = (const float*)d_in[13];

  const int Nn = in_sizes[0] / 128;
  const int E  = in_sizes[1] / 128;
  if (Nn <= 0 || E <= 0) return;

  char* ws = (char*)d_ws;
  size_t off = 0;
  auto alloc = [&](size_t b) { size_t o = off; off += (b + 255) & ~(size_t)255; return o; };
  const size_t o_idx   = alloc((size_t)2 * E * 4);
  const size_t o_cnt   = alloc((size_t)(Nn + 1) * 4);
  const size_t o_offs  = alloc((size_t)(Nn + 1) * 4);
  const size_t o_cur   = alloc((size_t)Nn * 4);
  const size_t o_order = alloc((size_t)E * 4);
  const size_t o_flag  = alloc(256);
  const size_t o_log   = alloc((size_t)E * 16);
  const size_t o_attw  = alloc((size_t)E * 16);
  const size_t o_inv   = alloc((size_t)Nn * 16);
  const size_t o_V     = alloc((size_t)E * 256);
  const size_t o_wbf   = alloc((size_t)115200 * 2);

  if (off > ws_size) {
    fb_kernel<<<(out_size + 255) / 256, 256, 0, stream>>>(hV, (float*)d_out, out_size);
    return;
  }

  int*   idx32  = (int*)(ws + o_idx);
  int*   cnt    = (int*)(ws + o_cnt);
  int*   offsP  = (int*)(ws + o_offs);
  int*   cur    = (int*)(ws + o_cur);
  int*   order  = (int*)(ws + o_order);
  int*   flag   = (int*)(ws + o_flag);
  float* logits = (float*)(ws + o_log);
  float* attw   = (float*)(ws + o_attw);
  float* invd   = (float*)(ws + o_inv);
  short* Vb     = (short*)(ws + o_V);
  short* wbf    = (short*)(ws + o_wbf);

  short* W1b = wbf;
  short* W2b = wbf + 49152;
  short* W3b = wbf + 65536;
  short* Wvb = wbf + 66048;
  short* Wob = wbf + 82432;
  short* Wgb = wbf + 98816;

  const int* src = idx32;
  const int* dst = idx32 + E;

  detect_kernel<<<1, 256, 0, stream>>>((const unsigned*)eidx, flag);
  convert_idx_kernel<<<(2 * E + 255) / 256, 256, 0, stream>>>(eidx, idx32, flag, 2 * E);
  hipMemsetAsync(cnt, 0, (size_t)(Nn + 1) * 4, stream);
  hipMemsetAsync(cur, 0, (size_t)Nn * 4, stream);
  count_kernel<<<(E + 255) / 256, 256, 0, stream>>>(src, cnt, E);
  scan_kernel<<<1, 1024, 0, stream>>>(cnt, offsP, Nn);
  scatter_kernel<<<(E + 255) / 256, 256, 0, stream>>>(src, offsP, cur, order, E);
  wcvt_kernel<<<(115200 + 255) / 256, 256, 0, stream>>>(B1w, B2w, B3w, WvW, WoW, GW, wbf);

  edge_kernel<<<(E + TE2 - 1) / TE2, 256, 0, stream>>>(
      hV, hE, src, dst, W1b, B1b, W2b, B2b, W3b, B3b, Wvb, WvB, logits, Vb, E);

  nm_kernel<<<(Nn + 3) / 4, 256, 0, stream>>>(logits, offsP, order, attw, invd, Nn);

  agg_kernel<<<(Nn + 3) / 4, 512, 0, stream>>>(
      hV, attw, invd, (const unsigned short*)Vb, offsP, order, Wob, Wgb, GB,
      (float*)d_out, Nn);
}

// Round 3
// 867.599 us; speedup vs baseline: 1.8485x; 1.2842x over previous
//
#include <hip/hip_runtime.h>
#include <math.h>

typedef __attribute__((ext_vector_type(8))) short bf16x8;
typedef __attribute__((ext_vector_type(4))) float f32x4;
typedef unsigned short u16;

__device__ __forceinline__ short f2bf(float x) {
  union { float f; unsigned u; } c; c.f = x;
  unsigned u = c.u;
  u += 0x7fffu + ((u >> 16) & 1u);
  return (short)(u >> 16);
}
__device__ __forceinline__ float bf2f(u16 b) {
  union { unsigned u; float f; } c; c.u = ((unsigned)b) << 16; return c.f;
}
__device__ __forceinline__ unsigned pack2(float a, float b) {
  return ((unsigned)(u16)f2bf(a)) | (((unsigned)(u16)f2bf(b)) << 16);
}
__device__ __forceinline__ float fast_erf(float x) {
  float ax = fabsf(x);
  float t = __frcp_rn(1.f + 0.3275911f * ax);
  float p = ((((1.061405429f * t - 1.453152027f) * t) + 1.421413741f) * t - 0.284496736f) * t + 0.254829592f;
  float y = 1.f - p * t * __expf(-ax * ax);
  return copysignf(y, x);
}
__device__ __forceinline__ void gload16(const void* g, void* l) {
  __builtin_amdgcn_global_load_lds(
      (const __attribute__((address_space(1))) void*)g,
      (__attribute__((address_space(3))) void*)l, 16, 0, 0);
}

// ---------------- index handling ----------------
__global__ void detect_kernel(const unsigned* __restrict__ idx32, int* __restrict__ flag) {
  __shared__ int anyNZ;
  if (threadIdx.x == 0) anyNZ = 0;
  __syncthreads();
  unsigned v = idx32[threadIdx.x * 2 + 1];
  if (v != 0u) atomicOr(&anyNZ, 1);
  __syncthreads();
  if (threadIdx.x == 0) *flag = (anyNZ == 0) ? 1 : 0;  // 1 => int64 input
}

__global__ void convert_idx_kernel(const void* __restrict__ in, int* __restrict__ s32,
                                   const int* __restrict__ flag, int twoE) {
  int i = blockIdx.x * 256 + threadIdx.x;
  if (i >= twoE) return;
  int f = *flag;
  int v = f ? (int)((const long long*)in)[i] : ((const int*)in)[i];
  s32[i] = v;
}

__global__ void count_kernel(const int* __restrict__ src, int* __restrict__ cnt, int E) {
  int i = blockIdx.x * 256 + threadIdx.x;
  if (i < E) atomicAdd(&cnt[src[i]], 1);
}

__global__ void __launch_bounds__(1024)
scan_kernel(const int* __restrict__ cnt, int* __restrict__ offs, int n) {
  __shared__ int sp[1024];
  int t = threadIdx.x;
  int chunk = (n + 1023) / 1024;
  int begin = t * chunk;
  int end = begin + chunk; if (end > n) end = n; if (begin > n) begin = n;
  int s = 0;
  for (int i = begin; i < end; ++i) s += cnt[i];
  sp[t] = s;
  __syncthreads();
  for (int o = 1; o < 1024; o <<= 1) {
    int v = (t >= o) ? sp[t - o] : 0;
    __syncthreads();
    sp[t] += v;
    __syncthreads();
  }
  int run = (t == 0) ? 0 : sp[t - 1];
  for (int i = begin; i < end; ++i) { offs[i] = run; run += cnt[i]; }
  if (t == 0) offs[n] = sp[1023];
}

__global__ void scatter_kernel(const int* __restrict__ src, const int* __restrict__ offs,
                               int* __restrict__ cur, int* __restrict__ order, int E) {
  int i = blockIdx.x * 256 + threadIdx.x;
  if (i >= E) return;
  int s = src[i];
  int p = offs[s] + atomicAdd(&cur[s], 1);
  order[p] = i;
}

// ---------------- weight fp32 -> bf16 ----------------
// layout: W1[128*384] | W2[128*128] | W3[4*128] | Wv[128*128] | Wo[128*128] | Wg[128*128]
__global__ void wcvt_kernel(const float* __restrict__ B1, const float* __restrict__ B2,
                            const float* __restrict__ B3, const float* __restrict__ Wv,
                            const float* __restrict__ Wo, const float* __restrict__ Wg,
                            short* __restrict__ o) {
  int i = blockIdx.x * 256 + threadIdx.x;
  const float* s; int base;
  if (i < 49152)       { s = B1; base = 0; }
  else if (i < 65536)  { s = B2; base = 49152; }
  else if (i < 66048)  { s = B3; base = 65536; }
  else if (i < 82432)  { s = Wv; base = 66048; }
  else if (i < 98816)  { s = Wo; base = 82432; }
  else if (i < 115200) { s = Wg; base = 98816; }
  else return;
  o[i] = f2bf(s[i - base]);
}

// ---------------- fp32 -> bf16 bulk convert ----------------
__global__ void cvtbf_kernel(const float* __restrict__ in, u16* __restrict__ out, long n8) {
  long i = (long)blockIdx.x * blockDim.x + threadIdx.x;
  long stride = (long)gridDim.x * blockDim.x;
  for (; i < n8; i += stride) {
    long b = i * 8;
    float4 a = *(const float4*)(in + b);
    float4 c = *(const float4*)(in + b + 4);
    uint4 u;
    u.x = pack2(a.x, a.y); u.y = pack2(a.z, a.w);
    u.z = pack2(c.x, c.y); u.w = pack2(c.z, c.w);
    *(uint4*)(out + b) = u;
  }
}

// ---------------- edge kernel ----------------
// TE=256 edges/block, 512 threads = 8 waves (4 row-groups x 2 col-groups).
// A staged bf16 via global_load_lds (XOR-swizzled source, swizzled reads).
// B fragments register-loaded from global bf16 weights (L2-hot).
__global__ void __launch_bounds__(512, 2)
edge_kernel(const u16* __restrict__ hVb, u16* __restrict__ hEV,
            const int* __restrict__ src, const int* __restrict__ dst,
            const short* __restrict__ W1, const float* __restrict__ b1,
            const short* __restrict__ W2, const float* __restrict__ b2,
            const short* __restrict__ W3b, const float* __restrict__ b3,
            const short* __restrict__ Wv, const float* __restrict__ bv,
            float* __restrict__ logits, int E) {
  __shared__ u16 sA[2][256 * 64];     // 64 KB, XOR-swizzle seg^(row&7)
  __shared__ u16 sH[256 * 128];       // 64 KB, XOR-swizzle seg^(row&15)
  __shared__ int sSrc[256];
  __shared__ int sDst[256];
  __shared__ float sPart[256][4][2];  // 8 KB

  const int t = threadIdx.x;
  const int eBase = blockIdx.x * 256;
  const int lane = t & 63;
  const int wid = t >> 6;
  const int wrow = (wid >> 1) * 64;
  const int wcol = (wid & 1) * 64;
  const int lrow = lane & 15;
  const int kgrp = lane >> 4;

  if (t < 256) { int e = eBase + t; sSrc[t] = src[min(e, E - 1)]; }
  else         { int e = eBase + t - 256; sDst[t - 256] = dst[min(e, E - 1)]; }
  __syncthreads();

  // per-thread staging sources (4 lines of 16B each; source pre-swizzled)
  const u16* pS[4]; const u16* pEp[4]; const u16* pD[4];
  int ldsOff[4];
#pragma unroll
  for (int i = 0; i < 4; ++i) {
    int line = t + i * 512;
    int row = line >> 3, seg = line & 7;
    int e = min(eBase + row, E - 1);
    int swz = (seg ^ (row & 7)) * 8;
    pS[i]  = hVb + (size_t)sSrc[row] * 128 + swz;
    pEp[i] = hEV + (size_t)e * 128 + swz;
    pD[i]  = hVb + (size_t)sDst[row] * 128 + swz;
    ldsOff[i] = wid * 1024 + i * 8192;   // byte offset (excl. lane*16, HW adds it)
  }

  float b1c[4], b2c[4], bvc[4];
#pragma unroll
  for (int nf = 0; nf < 4; ++nf) {
    int col = wcol + nf * 16 + lrow;
    b1c[nf] = b1[col]; b2c[nf] = b2[col]; bvc[nf] = bv[col];
  }

  f32x4 acc[4][4];
  bf16x8 bfr[8];

  auto ZACC = [&]() {
#pragma unroll
    for (int mi = 0; mi < 4; ++mi)
#pragma unroll
      for (int nf = 0; nf < 4; ++nf)
#pragma unroll
        for (int q = 0; q < 4; ++q) acc[mi][nf][q] = 0.f;
  };
  auto STAGE = [&](int cls, int k0, int buf) {
    char* base = (char*)&sA[buf][0];
#pragma unroll
    for (int i = 0; i < 4; ++i) {
      const u16* g = ((cls == 0) ? pS[i] : (cls == 1) ? pEp[i] : pD[i]) + k0;
      gload16(g, base + ldsOff[i]);
    }
  };
  auto LOADB = [&](const short* W, int ldk, int k0) {
#pragma unroll
    for (int nf = 0; nf < 4; ++nf)
#pragma unroll
      for (int ks = 0; ks < 2; ++ks)
        bfr[nf * 2 + ks] = *(const bf16x8*)(W + (size_t)(wcol + nf * 16 + lrow) * ldk + k0 + ks * 32 + kgrp * 8);
  };
  auto MFMAC = [&](int buf) {
#pragma unroll
    for (int ks = 0; ks < 2; ++ks) {
      bf16x8 a[4];
#pragma unroll
      for (int mi = 0; mi < 4; ++mi) {
        int row = wrow + mi * 16 + lrow;
        int seg = (ks * 4 + kgrp) ^ (row & 7);
        a[mi] = *(const bf16x8*)((char*)&sA[buf][0] + row * 128 + seg * 16);
      }
#pragma unroll
      for (int nf = 0; nf < 4; ++nf)
#pragma unroll
        for (int mi = 0; mi < 4; ++mi)
          acc[mi][nf] = __builtin_amdgcn_mfma_f32_16x16x32_bf16(a[mi], bfr[nf * 2 + ks], acc[mi][nf], 0, 0, 0);
    }
  };
  auto MFMAH = [&](int k2) {
#pragma unroll
    for (int ks = 0; ks < 2; ++ks) {
      bf16x8 a[4];
#pragma unroll
      for (int mi = 0; mi < 4; ++mi) {
        int row = wrow + mi * 16 + lrow;
        int seg = ((k2 >> 3) + ks * 4 + kgrp) ^ (row & 15);
        a[mi] = *(const bf16x8*)((char*)sH + row * 256 + seg * 16);
      }
#pragma unroll
      for (int nf = 0; nf < 4; ++nf)
#pragma unroll
        for (int mi = 0; mi < 4; ++mi)
          acc[mi][nf] = __builtin_amdgcn_mfma_f32_16x16x32_bf16(a[mi], bfr[nf * 2 + ks], acc[mi][nf], 0, 0, 0);
    }
  };
  // pipelined chunk: read buf(c&1), prefetch chunk c+1
  auto CHUNK = [&](const short* W, int ldk, int k0, int buf, int ncls, int nk0, int nbuf) {
    LOADB(W, ldk, k0);
    __builtin_amdgcn_sched_barrier(0);
    STAGE(ncls, nk0, nbuf);
    asm volatile("s_waitcnt vmcnt(4)" ::: "memory");
    __builtin_amdgcn_sched_barrier(0);
    __builtin_amdgcn_s_barrier();
    MFMAC(buf);
    asm volatile("s_waitcnt lgkmcnt(0)" ::: "memory");
    __builtin_amdgcn_sched_barrier(0);
    __builtin_amdgcn_s_barrier();
  };

  // ---- prologue: stage chunk0 (hVb[src] k0..63) into buf0
  STAGE(0, 0, 0);

  // ---- layer 1: X[256,384] @ W1^T, chunks c0..c5; prefetch table
  ZACC();
  CHUNK(W1, 384, 0,   0, 0, 64, 1);   // c0 ; stage c1: hVsrc hi
  CHUNK(W1, 384, 64,  1, 1, 0,  0);   // c1 ; stage c2: hE lo
  CHUNK(W1, 384, 128, 0, 1, 64, 1);   // c2 ; stage c3: hE hi
  CHUNK(W1, 384, 192, 1, 2, 0,  0);   // c3 ; stage c4: hVdst lo
  CHUNK(W1, 384, 256, 0, 2, 64, 1);   // c4 ; stage c5: hVdst hi
  CHUNK(W1, 384, 320, 1, 1, 0,  0);   // c5 ; stage c6: hE lo (for V)

  // ---- epilogue 1: sH = relu(acc + b1), swizzled
#pragma unroll
  for (int mi = 0; mi < 4; ++mi)
#pragma unroll
    for (int nf = 0; nf < 4; ++nf)
#pragma unroll
      for (int q = 0; q < 4; ++q) {
        int row = wrow + mi * 16 + kgrp * 4 + q;
        int col = wcol + nf * 16 + lrow;
        u16 v = (u16)f2bf(fmaxf(acc[mi][nf][q] + b1c[nf], 0.f));
        int seg = (col >> 3) ^ (row & 15);
        *(u16*)((char*)sH + row * 256 + seg * 16 + (col & 7) * 2) = v;
      }
  asm volatile("s_waitcnt lgkmcnt(0)" ::: "memory");
  __builtin_amdgcn_sched_barrier(0);
  __builtin_amdgcn_s_barrier();

  // ---- V = gelu(hE @ Wv^T + bv): chunks c6,c7 (hEb restaged, L2-hot)
  ZACC();
  // c6: reads buf0, stage c7 (hE hi) -> buf1
  LOADB(Wv, 128, 0);
  __builtin_amdgcn_sched_barrier(0);
  STAGE(1, 64, 1);
  asm volatile("s_waitcnt vmcnt(4)" ::: "memory");
  __builtin_amdgcn_sched_barrier(0);
  __builtin_amdgcn_s_barrier();
  MFMAC(0);
  asm volatile("s_waitcnt lgkmcnt(0)" ::: "memory");
  __builtin_amdgcn_sched_barrier(0);
  __builtin_amdgcn_s_barrier();
  // c7: reads buf1, no stage
  LOADB(Wv, 128, 64);
  asm volatile("s_waitcnt vmcnt(0)" ::: "memory");
  __builtin_amdgcn_sched_barrier(0);
  __builtin_amdgcn_s_barrier();
  MFMAC(1);
  asm volatile("s_waitcnt lgkmcnt(0)" ::: "memory");
  __builtin_amdgcn_sched_barrier(0);
  __builtin_amdgcn_s_barrier();

  // ---- V epilogue: gelu -> sV (reuse sA area, swizzled), then coalesced store
  {
    char* sV = (char*)&sA[0][0];
#pragma unroll
    for (int mi = 0; mi < 4; ++mi)
#pragma unroll
      for (int nf = 0; nf < 4; ++nf)
#pragma unroll
        for (int q = 0; q < 4; ++q) {
          int row = wrow + mi * 16 + kgrp * 4 + q;
          int col = wcol + nf * 16 + lrow;
          float x = acc[mi][nf][q] + bvc[nf];
          float g = 0.5f * x * (1.0f + fast_erf(x * 0.70710678118654752f));
          int b = col >> 6, cc = col & 63;
          int seg = (cc >> 3) ^ (row & 7);
          *(u16*)(sV + b * 32768 + row * 128 + seg * 16 + (cc & 7) * 2) = (u16)f2bf(g);
        }
    asm volatile("s_waitcnt lgkmcnt(0)" ::: "memory");
    __builtin_amdgcn_sched_barrier(0);
    __builtin_amdgcn_s_barrier();
#pragma unroll
    for (int i = 0; i < 8; ++i) {
      int flat = t + i * 512;            // 0..4095 16B-lines
      int row = flat >> 4, g16 = flat & 15;
      int b = g16 >> 3, seg = (g16 & 7) ^ (row & 7);
      uint4 v = *(const uint4*)(sV + b * 32768 + row * 128 + seg * 16);
      int e = eBase + row;
      if (e < E) *(uint4*)(hEV + (size_t)e * 128 + g16 * 8) = v;
    }
  }

  // ---- layer 2: H2 = relu(sH @ W2^T + b2) folded with layer 3
  ZACC();
  LOADB(W2, 128, 0);
  MFMAH(0);
  LOADB(W2, 128, 64);
  MFMAH(64);

  {
    float w3v[4][4];
#pragma unroll
    for (int nf = 0; nf < 4; ++nf) {
      int col = wcol + nf * 16 + lrow;
#pragma unroll
      for (int h = 0; h < 4; ++h) w3v[h][nf] = bf2f((u16)W3b[h * 128 + col]);
    }
#pragma unroll
    for (int mi = 0; mi < 4; ++mi)
#pragma unroll
      for (int q = 0; q < 4; ++q) {
        float p0 = 0.f, p1 = 0.f, p2 = 0.f, p3 = 0.f;
#pragma unroll
        for (int nf = 0; nf < 4; ++nf) {
          float x = fmaxf(acc[mi][nf][q] + b2c[nf], 0.f);
          p0 += x * w3v[0][nf]; p1 += x * w3v[1][nf];
          p2 += x * w3v[2][nf]; p3 += x * w3v[3][nf];
        }
#pragma unroll
        for (int o = 1; o < 16; o <<= 1) {
          p0 += __shfl_xor(p0, o); p1 += __shfl_xor(p1, o);
          p2 += __shfl_xor(p2, o); p3 += __shfl_xor(p3, o);
        }
        if (lrow < 4) {
          float pw = (lrow == 0) ? p0 : (lrow == 1) ? p1 : (lrow == 2) ? p2 : p3;
          sPart[wrow + mi * 16 + kgrp * 4 + q][lrow][wid & 1] = pw;
        }
      }
  }
  asm volatile("s_waitcnt lgkmcnt(0)" ::: "memory");
  __builtin_amdgcn_sched_barrier(0);
  __builtin_amdgcn_s_barrier();
  if (t < 256) {
    int e = eBase + t;
    if (e < E) {
      float4 lg;
      lg.x = (sPart[t][0][0] + sPart[t][0][1] + b3[0]) * 0.17677669529663687f;
      lg.y = (sPart[t][1][0] + sPart[t][1][1] + b3[1]) * 0.17677669529663687f;
      lg.z = (sPart[t][2][0] + sPart[t][2][1] + b3[2]) * 0.17677669529663687f;
      lg.w = (sPart[t][3][0] + sPart[t][3][1] + b3[3]) * 0.17677669529663687f;
      *(float4*)(logits + (size_t)e * 4) = lg;
    }
  }
}

// ---------------- node kernels ----------------
__global__ void __launch_bounds__(256)
nm_kernel(const float* __restrict__ logits, const int* __restrict__ offs,
          const int* __restrict__ order, float* __restrict__ attw,
          float* __restrict__ inv, int nN) {
  const int wid = threadIdx.x >> 6, lane = threadIdx.x & 63;
  const int nW = gridDim.x * 4;
  for (int v = blockIdx.x * 4 + wid; v < nN; v += nW) {
    const int base = offs[v];
    const int deg = offs[v + 1] - base;
    float m0 = -3e38f, m1 = -3e38f, m2 = -3e38f, m3 = -3e38f;
    for (int i = lane; i < deg; i += 64) {
      int e = order[base + i];
      float4 l = *(const float4*)(logits + (size_t)e * 4);
      m0 = fmaxf(m0, l.x); m1 = fmaxf(m1, l.y);
      m2 = fmaxf(m2, l.z); m3 = fmaxf(m3, l.w);
    }
#pragma unroll
    for (int o = 32; o > 0; o >>= 1) {
      m0 = fmaxf(m0, __shfl_xor(m0, o)); m1 = fmaxf(m1, __shfl_xor(m1, o));
      m2 = fmaxf(m2, __shfl_xor(m2, o)); m3 = fmaxf(m3, __shfl_xor(m3, o));
    }
    float d0 = 0.f, d1 = 0.f, d2 = 0.f, d3 = 0.f;
    for (int i = lane; i < deg; i += 64) {
      int e = order[base + i];
      float4 l = *(const float4*)(logits + (size_t)e * 4);
      float4 ex;
      ex.x = __expf(l.x - m0); ex.y = __expf(l.y - m1);
      ex.z = __expf(l.z - m2); ex.w = __expf(l.w - m3);
      *(float4*)(attw + (size_t)e * 4) = ex;
      d0 += ex.x; d1 += ex.y; d2 += ex.z; d3 += ex.w;
    }
#pragma unroll
    for (int o = 32; o > 0; o >>= 1) {
      d0 += __shfl_xor(d0, o); d1 += __shfl_xor(d1, o);
      d2 += __shfl_xor(d2, o); d3 += __shfl_xor(d3, o);
    }
    if (lane < 4) {
      float dv = (lane == 0) ? d0 : (lane == 1) ? d1 : (lane == 2) ? d2 : d3;
      inv[(size_t)v * 4 + lane] = (dv > 0.f) ? 1.f / dv : 0.f;
    }
  }
}

__device__ __forceinline__ float dot8(const float* ag, uint4 w) {
  unsigned wr[4] = {w.x, w.y, w.z, w.w};
  float s = 0.f;
#pragma unroll
  for (int q = 0; q < 4; ++q) {
    s += ag[2 * q]     * bf2f((u16)(wr[q] & 0xffffu));
    s += ag[2 * q + 1] * bf2f((u16)(wr[q] >> 16));
  }
  return s;
}

// dim-parallel aggregation (4-deep unrolled edge loop) + fused output GEMV.
__global__ void __launch_bounds__(512)
agg_kernel(const float* __restrict__ hV, const float* __restrict__ attw,
           const float* __restrict__ inv, const u16* __restrict__ V,
           const int* __restrict__ offs, const int* __restrict__ order,
           const short* __restrict__ Wo, const short* __restrict__ Wg,
           const float* __restrict__ gb, float* __restrict__ out, int nN) {
  __shared__ float sAgg[4][132];
  const int vl = threadIdx.x >> 7;
  const int d = threadIdx.x & 127;
  const int h = d >> 5;
  const int v = blockIdx.x * 4 + vl;
  if (v < nN) {
    const int base = offs[v];
    const int deg = offs[v + 1] - base;
    float s = 0.f;
    int i = 0;
    for (; i + 4 <= deg; i += 4) {
      int e0 = order[base + i], e1 = order[base + i + 1];
      int e2 = order[base + i + 2], e3 = order[base + i + 3];
      float w0 = attw[(size_t)e0 * 4 + h], w1 = attw[(size_t)e1 * 4 + h];
      float w2 = attw[(size_t)e2 * 4 + h], w3 = attw[(size_t)e3 * 4 + h];
      float v0 = bf2f(V[(size_t)e0 * 128 + d]), v1 = bf2f(V[(size_t)e1 * 128 + d]);
      float v2 = bf2f(V[(size_t)e2 * 128 + d]), v3 = bf2f(V[(size_t)e3 * 128 + d]);
      s += w0 * v0; s += w1 * v1; s += w2 * v2; s += w3 * v3;
    }
    for (; i < deg; ++i) {
      int e = order[base + i];
      s += attw[(size_t)e * 4 + h] * bf2f(V[(size_t)e * 128 + d]);
    }
    sAgg[vl][d] = s * inv[(size_t)v * 4 + h];
  }
  __syncthreads();
  if (v < nN) {
    float o = 0.f, g = 0.f;
#pragma unroll 4
    for (int k = 0; k < 128; k += 8) {
      float a8[8];
#pragma unroll
      for (int q = 0; q < 8; ++q) a8[q] = sAgg[vl][k + q];
      uint4 wo = *(const uint4*)(Wo + (size_t)d * 128 + k);
      uint4 wg = *(const uint4*)(Wg + (size_t)d * 128 + k);
      o += dot8(a8, wo);
      g += dot8(a8, wg);
    }
    float gate = 1.f / (1.f + __expf(-(g + gb[d])));
    out[(size_t)v * 128 + d] = hV[(size_t)v * 128 + d] + o * gate;
  }
}

// ---------------- fallback (ws too small marker) ----------------
__global__ void fb_kernel(const float* __restrict__ hV, float* __restrict__ out, int n) {
  int i = blockIdx.x * 256 + threadIdx.x;
  if (i < n) out[i] = hV[i] + 0.5f;
}

extern "C" void kernel_launch(void* const* d_in, const int* in_sizes, int n_in,
                              void* d_out, int out_size, void* d_ws, size_t ws_size,
                              hipStream_t stream) {
  const float* hV   = (const float*)d_in[0];
  const float* hE   = (const float*)d_in[1];
  const void*  eidx = d_in[2];
  const float* WvW  = (const float*)d_in[3];
  const float* WvB  = (const float*)d_in[4];
  const float* B1w  = (const float*)d_in[5];
  const float* B1b  = (const float*)d_in[6];
  const float* B2w  = (const float*)d_in[7];
  const float* B2b  = (const float*)d_in[8];
  const float* B3w  = (const float*)d_in[9];
  const float* B3b  = (const float*)d_in[10];
  const float* WoW  = (const float*)d_in[11];
  const float* GW   = (const float*)d_in[12];
  const float* GB   = (const float*)d_in[13];

  const int Nn = in_sizes[0] / 128;
  const int E  = in_sizes[1] / 128;
  if (Nn <= 0 || E <= 0) return;

  char* ws = (char*)d_ws;
  size_t off = 0;
  auto alloc = [&](size_t b) { size_t o = off; off += (b + 255) & ~(size_t)255; return o; };
  const size_t o_idx   = alloc((size_t)2 * E * 4);
  const size_t o_cnt   = alloc((size_t)(Nn + 1) * 4);
  const size_t o_offs  = alloc((size_t)(Nn + 1) * 4);
  const size_t o_cur   = alloc((size_t)Nn * 4);
  const size_t o_order = alloc((size_t)E * 4);
  const size_t o_flag  = alloc(256);
  const size_t o_log   = alloc((size_t)E * 16);
  const size_t o_attw  = alloc((size_t)E * 16);
  const size_t o_inv   = alloc((size_t)Nn * 16);
  const size_t o_V     = alloc((size_t)E * 256);   // hEb (bf16) then overwritten by V
  const size_t o_hVb   = alloc((size_t)Nn * 256);
  const size_t o_wbf   = alloc((size_t)115200 * 2);

  if (off > ws_size) {
    fb_kernel<<<(out_size + 255) / 256, 256, 0, stream>>>(hV, (float*)d_out, out_size);
    return;
  }

  int*   idx32  = (int*)(ws + o_idx);
  int*   cnt    = (int*)(ws + o_cnt);
  int*   offsP  = (int*)(ws + o_offs);
  int*   cur    = (int*)(ws + o_cur);
  int*   order  = (int*)(ws + o_order);
  int*   flag   = (int*)(ws + o_flag);
  float* logits = (float*)(ws + o_log);
  float* attw   = (float*)(ws + o_attw);
  float* invd   = (float*)(ws + o_inv);
  u16*   hEV    = (u16*)(ws + o_V);
  u16*   hVb    = (u16*)(ws + o_hVb);
  short* wbf    = (short*)(ws + o_wbf);

  short* W1b = wbf;
  short* W2b = wbf + 49152;
  short* W3b = wbf + 65536;
  short* Wvb = wbf + 66048;
  short* Wob = wbf + 82432;
  short* Wgb = wbf + 98816;

  const int* src = idx32;
  const int* dst = idx32 + E;

  detect_kernel<<<1, 256, 0, stream>>>((const unsigned*)eidx, flag);
  convert_idx_kernel<<<(2 * E + 255) / 256, 256, 0, stream>>>(eidx, idx32, flag, 2 * E);
  hipMemsetAsync(cnt, 0, (size_t)(Nn + 1) * 4, stream);
  hipMemsetAsync(cur, 0, (size_t)Nn * 4, stream);
  count_kernel<<<(E + 255) / 256, 256, 0, stream>>>(src, cnt, E);
  scan_kernel<<<1, 1024, 0, stream>>>(cnt, offsP, Nn);
  scatter_kernel<<<(E + 255) / 256, 256, 0, stream>>>(src, offsP, cur, order, E);
  wcvt_kernel<<<(115200 + 255) / 256, 256, 0, stream>>>(B1w, B2w, B3w, WvW, WoW, GW, wbf);
  cvtbf_kernel<<<512, 256, 0, stream>>>(hV, hVb, (long)Nn * 16);
  cvtbf_kernel<<<2048, 256, 0, stream>>>(hE, hEV, (long)E * 16);

  edge_kernel<<<(E + 255) / 256, 512, 0, stream>>>(
      hVb, hEV, src, dst, W1b, B1b, W2b, B2b, W3b, B3b, Wvb, WvB, logits, E);

  nm_kernel<<<(Nn + 3) / 4, 256, 0, stream>>>(logits, offsP, order, attw, invd, Nn);

  agg_kernel<<<(Nn + 3) / 4, 512, 0, stream>>>(
      hV, attw, invd, hEV, offsP, order, Wob, Wgb, GB,
      (float*)d_out, Nn);
}